// Round 6
// baseline (492.738 us; speedup 1.0000x reference)
//
#include <hip/hip_runtime.h>
#include <cstdint>
#include <cstddef>

// FeedForward: GroupNorm(8) -> conv1x1 C->2C -> GELU(exact) -> conv1x1 2C->C -> +x
// B=16, C=512, L=4096. ALL I/O FP32. Internal: bf16 MFMA, fp32 accum.
//
// R10 = R9 with hardened inline-asm (R9 died at container level, no counters;
// R8 -- same structure, C++ ds_reads -- passed, so the asm ds_read is the only
// new suspect besides infra flake):
//  - ds_read_b128 asm output is now u32x4 (conventional VGPR-quad operand
//    class, HK-style) bit-cast to bf16x8, instead of a bf16-vector asm operand.
//  - __syncthreads() after the post-loop vmcnt(0) drain: guaranteed-clean
//    LDS-DMA state at s_endpgm.
// R9 theory (kept): compiler's waitcnt pass conservatively inserts
// s_waitcnt vmcnt(0) before C++-level ds_reads that may alias outstanding
// global_load_lds LDS-DMA -> R8's counted-vmcnt pipeline was silently defeated
// (MfmaUtil 16.7%, nothing saturated). Fix: asm ds_read_b128 (invisible to the
// pass) + explicit s_waitcnt lgkmcnt(0) + sched_barrier(0) before each MFMA
// cluster (guide rule 18).
// Kept: 4-phase 256x256 8-wave schedule, counted vmcnt(8) (never 0 in loop),
// s_setprio around MFMA, XOR slot swizzle, A&S erf GELU, swapped mfma(bb,af)
// epilogues (gemm1 i-outer full-sector stores), XCD swizzles.

typedef unsigned short u16;
typedef unsigned int u32;
typedef __attribute__((ext_vector_type(8))) __bf16 bf16x8;
typedef __attribute__((ext_vector_type(4))) u32 u32x4;
typedef __attribute__((ext_vector_type(4))) float floatx4;

#define BKK 64

__device__ __forceinline__ u16 f2bf(float f) {
    union { float f; u32 u; } v; v.f = f;
    u32 u = v.u;
    return (u16)((u + 0x7fffu + ((u >> 16) & 1u)) >> 16);  // RNE
}

// GELU(v) = 0.5 v (1 + erf(v/sqrt(2))); erf via A&S 7.1.26, |err| <= 1.5e-7.
__device__ __forceinline__ float gelu_exact(float v) {
    const float x = fabsf(v) * 0.70710678118654752f;
    const float t = __builtin_amdgcn_rcpf(fmaf(0.3275911f, x, 1.0f));
    float p = fmaf(1.061405429f, t, -1.453152027f);
    p = fmaf(p, t, 1.421413741f);
    p = fmaf(p, t, -0.284496736f);
    p = fmaf(p, t, 0.254829592f);
    p = p * t;
    const float e = __expf(-x * x);
    const float er = fmaf(-p, e, 1.0f);
    const float s = copysignf(er, v);
    return 0.5f * v * (1.0f + s);
}

__device__ __forceinline__ void async_cp16(u16* lds, const u16* g) {
    __builtin_amdgcn_global_load_lds(
        (const __attribute__((address_space(1))) u32*)g,
        (__attribute__((address_space(3))) u32*)lds,
        16, 0, 0);
}

// ds_read_b128 via inline asm: invisible to the compiler's waitcnt pass, so no
// conservative vmcnt(0) drains against in-flight global_load_lds LDS-DMA.
// Output is a u32 quad (conventional operand class); completion enforced by
// explicit s_waitcnt lgkmcnt(0) + sched_barrier(0) before use (rule 18).
__device__ __forceinline__ bf16x8 ds_read16(const u16* p) {
    u32x4 r;
    const u32 off = (u32)(size_t)(const __attribute__((address_space(3))) u16*)p;
    asm volatile("ds_read_b128 %0, %1" : "=&v"(r) : "v"(off));
    return __builtin_bit_cast(bf16x8, r);
}

// ---------------- kernel 1: partial group stats ----------------
__global__ __launch_bounds__(256) void gn_stats_partial(const float* __restrict__ x,
                                                        float* __restrict__ pstats) {
    const int bx = blockIdx.x;  // bg*8 + slice
    const float4* p = (const float4*)(x + (size_t)(bx >> 3) * 262144 + (size_t)(bx & 7) * 32768);
    float s = 0.f, ss = 0.f;
    for (int i = threadIdx.x; i < 8192; i += 256) {
        float4 v = p[i];
        s += v.x + v.y + v.z + v.w;
        ss += v.x * v.x + v.y * v.y + v.z * v.z + v.w * v.w;
    }
#pragma unroll
    for (int off = 32; off > 0; off >>= 1) {
        s  += __shfl_down(s, off, 64);
        ss += __shfl_down(ss, off, 64);
    }
    __shared__ float rs[8];
    const int wv = threadIdx.x >> 6;
    if ((threadIdx.x & 63) == 0) { rs[wv * 2] = s; rs[wv * 2 + 1] = ss; }
    __syncthreads();
    if (threadIdx.x == 0) {
        pstats[bx * 2]     = rs[0] + rs[2] + rs[4] + rs[6];
        pstats[bx * 2 + 1] = rs[1] + rs[3] + rs[5] + rs[7];
    }
}

// ---------------- kernel 2: weights fp32 -> bf16 ----------------
__global__ __launch_bounds__(256) void conv_w(const float* __restrict__ w1,
                                              const float* __restrict__ w2,
                                              u16* __restrict__ wb) {
    const int idx = (blockIdx.x * 256 + threadIdx.x) * 4;  // < 1048576
    const float4 v = (idx < 524288) ? *(const float4*)(w1 + idx)
                                    : *(const float4*)(w2 + (idx - 524288));
    ushort4 o;
    o.x = f2bf(v.x); o.y = f2bf(v.y); o.z = f2bf(v.z); o.w = f2bf(v.w);
    *(ushort4*)(wb + idx) = o;
}

// ---------------- kernel 3: normalize + transpose (fp32 -> bf16) ----------------
__global__ __launch_bounds__(256) void gn_norm_tr(const float* __restrict__ x,
                                                  const float* __restrict__ gamma,
                                                  const float* __restrict__ beta,
                                                  const float* __restrict__ pstats,
                                                  u16* __restrict__ xnT, int b0) {
    __shared__ u16 T[64][72];  // [l][c], c-groups XOR-swizzled by (l>>3)&7
    const int bx = blockIdx.x;
    const int lt = bx & 63, ct = (bx >> 6) & 7, bl = bx >> 9;
    const int b = b0 + bl;
    const int c0 = ct * 64, l0 = lt * 64;
    const int g = c0 >> 6;   // tile spans exactly one group
    float S = 0.f, SS = 0.f;
#pragma unroll
    for (int s2 = 0; s2 < 8; ++s2) {
        S  += pstats[((b * 8 + g) * 8 + s2) * 2];
        SS += pstats[((b * 8 + g) * 8 + s2) * 2 + 1];
    }
    const float inv = 1.f / 262144.f;
    const float mean = S * inv;
    const float var = SS * inv - mean * mean;  // population var (jnp.var)
    const float rstd = rsqrtf(var + 1e-5f);

    const int t = threadIdx.x;
    const int cl = t >> 3;          // 0..31
    const int lo = (t & 7) * 8;     // 8 l's per thread
    const int sw = t & 7;           // == (l>>3)&7 for this thread's l's
#pragma unroll
    for (int h = 0; h < 2; ++h) {
        const int c = c0 + cl + h * 32;
        const float sc = rstd * gamma[c];
        const float sh = beta[c] - mean * sc;
        const float* src = x + ((size_t)(b * 512 + c) * 4096 + l0 + lo);
        float4 a = *(const float4*)src;
        float4 bq = *(const float4*)(src + 4);
        float vv[8] = {a.x, a.y, a.z, a.w, bq.x, bq.y, bq.z, bq.w};
        const int ccol = cl + h * 32;
        const int cg = ccol >> 3, cr = ccol & 7;
#pragma unroll
        for (int q = 0; q < 8; ++q)
            T[lo + q][((cg ^ sw) << 3) + cr] = f2bf(fmaf(vv[q], sc, sh));
    }
    __syncthreads();
    const int ll = t >> 3;
    const int co = (t & 7) * 8, cog = t & 7;
#pragma unroll
    for (int h = 0; h < 2; ++h) {
        const int l = ll + h * 32;
        const uint4* srcv = (const uint4*)&T[l][(cog ^ ((l >> 3) & 7)) << 3];
        *(uint4*)(xnT + ((size_t)(bl * 4096 + l0 + l) * 512 + c0 + co)) = *srcv;
    }
}

// ---------------- 256x256 8-wave GEMM core ----------------
// C[m][n] = sum_k A[m][k]*B[n][k], BK=64, NT = K/64 tiles.
// LDS per op: [buf2][kh2][256 rows][4 slots][8 u16] = 64KB; slot holds k-group
// g2 = slot ^ ((row>>1)&3) (k = tile*64 + kh*32 + g2*8 + 0..7). Read with
// sl4 = quad ^ ((fr>>1)&3) -> lane's k-group == quad.
// Schedule per tile t (4 phases), per phase:
//   asm ds_read frags; stage one half (2 gloads); s_barrier;
//   lgkmcnt(0)+sched_barrier; setprio(1); 16 MFMA; setprio(0); [vmcnt(8)]; s_barrier
// vmcnt(8) only at p2/p4 -- never 0 in the loop.
// WAR safe: region reads complete at that phase's lgkmcnt(0), before the
// phase-closing barrier; restage of the region is >=1 barrier later.
// RAW safe: per-wave vmcnt(8) before the closing barrier certifies all waves'
// slices of the next-needed half landed (counting verified: prologue 12,
// +2/phase; at p2-end certifies t.kh1, at p4-end certifies (t+1).kh0).
// Tail: stage indices wrap mod NT (NT even -> same parity; dummy loads
// in-bounds, land in slots never read again).
__device__ __forceinline__ void gemm_core256(const u16* __restrict__ Ag,
                                             const u16* __restrict__ Bg,
                                             int K, int NT, floatx4 acc[8][4],
                                             u16* lA, u16* lB,
                                             int wm, int wn, int fr, int quad) {
    const int tid = threadIdx.x;
    const int sl4 = quad ^ ((fr >> 1) & 3);

    // per-thread staging bases (hoisted): two 16B slices per half per op
    const int i0 = tid, i1 = 512 + tid;
    const int r0 = i0 >> 2, g0 = (i0 & 3) ^ ((r0 >> 1) & 3);
    const int r1 = i1 >> 2, g1 = (i1 & 3) ^ ((r1 >> 1) & 3);
    const u16* sA0 = Ag + (size_t)r0 * K + g0 * 8;
    const u16* sA1 = Ag + (size_t)r1 * K + g1 * 8;
    const u16* sB0 = Bg + (size_t)r0 * K + g0 * 8;
    const u16* sB1 = Bg + (size_t)r1 * K + g1 * 8;
    u16* dA0 = lA + i0 * 8; u16* dA1 = lA + i1 * 8;
    u16* dB0 = lB + i0 * 8; u16* dB1 = lB + i1 * 8;

#define STAGE_A(t_, kh_) { const int o_ = (t_) * BKK + (kh_) * 32;              \
        const int d_ = (((t_) & 1) * 16384 + (kh_) * 8192);                     \
        async_cp16(dA0 + d_, sA0 + o_); async_cp16(dA1 + d_, sA1 + o_); }
#define STAGE_B(t_, kh_) { const int o_ = (t_) * BKK + (kh_) * 32;              \
        const int d_ = (((t_) & 1) * 16384 + (kh_) * 8192);                     \
        async_cp16(dB0 + d_, sB0 + o_); async_cp16(dB1 + d_, sB1 + o_); }

    bf16x8 bb[4];

    // prologue: t0 full + t1.kh0 (12 loads)
    STAGE_A(0, 0); STAGE_B(0, 0);
    STAGE_A(0, 1); STAGE_B(0, 1);
    STAGE_A(1, 0); STAGE_B(1, 0);
    asm volatile("s_waitcnt vmcnt(8)" ::: "memory");  // t0.kh0 landed
    __builtin_amdgcn_sched_barrier(0);
    __builtin_amdgcn_s_barrier();

#define VM8 { asm volatile("s_waitcnt vmcnt(8)" ::: "memory"); \
              __builtin_amdgcn_sched_barrier(0); }

#define PHASE(kh_, ih_, STG, DOVM)                                              \
    {                                                                           \
        const u16* bA = lA + ((t & 1) * 16384 + (kh_) * 8192);                  \
        const u16* bB = lB + ((t & 1) * 16384 + (kh_) * 8192);                  \
        bf16x8 af[4];                                                           \
        _Pragma("unroll")                                                       \
        for (int i = 0; i < 4; ++i)                                             \
            af[i] = ds_read16(bA + ((((wm + (ih_)*64 + i*16 + fr) << 2) | sl4) * 8)); \
        if ((ih_) == 0) {                                                       \
            _Pragma("unroll")                                                   \
            for (int j = 0; j < 4; ++j)                                         \
                bb[j] = ds_read16(bB + ((((wn + j*16 + fr) << 2) | sl4) * 8));  \
        }                                                                       \
        STG;                                                                    \
        __builtin_amdgcn_s_barrier();                                           \
        asm volatile("s_waitcnt lgkmcnt(0)" ::: "memory");                      \
        __builtin_amdgcn_sched_barrier(0);                                      \
        __builtin_amdgcn_s_setprio(1);                                          \
        _Pragma("unroll")                                                       \
        for (int j = 0; j < 4; ++j) {                                           \
            _Pragma("unroll")                                                   \
            for (int i = 0; i < 4; ++i)                                         \
                acc[(ih_)*4 + i][j] = __builtin_amdgcn_mfma_f32_16x16x32_bf16(  \
                    bb[j], af[i], acc[(ih_)*4 + i][j], 0, 0, 0);                \
        }                                                                       \
        __builtin_amdgcn_s_setprio(0);                                          \
        DOVM;                                                                   \
        __builtin_amdgcn_s_barrier();                                           \
    }

    for (int t = 0; t < NT; ++t) {
        int t1 = t + 1; if (t1 >= NT) t1 -= NT;
        int t2 = t + 2; if (t2 >= NT) t2 -= NT;
        PHASE(0, 0, STAGE_A(t1, 1), {})
        PHASE(0, 1, STAGE_B(t1, 1), VM8)
        PHASE(1, 0, STAGE_A(t2, 0), {})
        PHASE(1, 1, STAGE_B(t2, 0), VM8)
    }
#undef PHASE
#undef VM8
#undef STAGE_A
#undef STAGE_B
    // Drain all in-flight LDS-DMA, then full-barrier: guaranteed-clean state
    // before epilogue / s_endpgm (R8 fault fix, hardened).
    asm volatile("s_waitcnt vmcnt(0)" ::: "memory");
    __builtin_amdgcn_sched_barrier(0);
    __syncthreads();
}

// ---------------- kernel 4: GEMM1 + bias + exact GELU -> h1T (bf16) ----------------
// A = xnT [flat l][512], B = w1b [1024][512]; out h1T [flat l][1024].
__global__ __launch_bounds__(512, 2) void gemm1(const u16* __restrict__ xnT,
                                                const u16* __restrict__ w1b,
                                                const float* __restrict__ b1,
                                                u16* __restrict__ h1T) {
    __shared__ u16 lds[65536];  // 128 KiB: A 64KB | B 64KB
    u16* lA = lds;
    u16* lB = lds + 32768;
    const int bx = blockIdx.x;
    // XCD swizzle: mt = group*8 + xcd; 4 nt's of one mt adjacent (dist 8, same xcd).
    const int xcd = bx & 7;
    const int nt = (bx >> 3) & 3;
    const int mt = (bx >> 5) * 8 + xcd;
    const int tid = threadIdx.x, lane = tid & 63, wid = tid >> 6;
    const int wm = (wid >> 2) * 128, wn = (wid & 3) * 64;
    const int fr = lane & 15, quad = lane >> 4;
    floatx4 acc[8][4];
#pragma unroll
    for (int i = 0; i < 8; ++i)
#pragma unroll
        for (int j = 0; j < 4; ++j) acc[i][j] = (floatx4){0.f, 0.f, 0.f, 0.f};

    gemm_core256(xnT + (size_t)(mt * 256) * 512, w1b + (size_t)(nt * 256) * 512,
                 512, 8, acc, lA, lB, wm, wn, fr, quad);

    // swapped layout: m <- col (fr), n <- row (quad*4 + reg)
    const int mb = mt * 256 + wm + fr;
    const int nb = nt * 256 + wn + quad * 4;
    float4 bv[4];
#pragma unroll
    for (int j = 0; j < 4; ++j) bv[j] = *(const float4*)(b1 + nb + j * 16);
    // i-outer/j-inner: each row's 128B span written by 4 back-to-back stores
    // (full 64B sectors -> L2 write merging; j-outer caused 1.77x RMW amp).
#pragma unroll
    for (int i = 0; i < 8; ++i) {
        const int m = mb + i * 16;
        u16* drow = h1T + (size_t)m * 1024 + nb;
#pragma unroll
        for (int j = 0; j < 4; ++j) {
            ushort4 o;
            o.x = f2bf(gelu_exact(acc[i][j][0] + bv[j].x));
            o.y = f2bf(gelu_exact(acc[i][j][1] + bv[j].y));
            o.z = f2bf(gelu_exact(acc[i][j][2] + bv[j].z));
            o.w = f2bf(gelu_exact(acc[i][j][3] + bv[j].w));
            *(ushort4*)(drow + j * 16) = o;
        }
    }
}

// ---------------- kernel 5: GEMM2 + bias + residual -> out (fp32) ----------------
// A = w2b [512][1024], B = h1T [flat l][1024]; out[b][c][l] = acc + b2 + x.
__global__ __launch_bounds__(512, 2) void gemm2(const u16* __restrict__ w2b,
                                                const u16* __restrict__ h1T,
                                                const float* __restrict__ b2,
                                                const float* __restrict__ x,
                                                float* __restrict__ out, int b0) {
    __shared__ u16 lds[65536];
    u16* lA = lds;
    u16* lB = lds + 32768;
    const int bx = blockIdx.x;
    // XCD swizzle: nt = group*8 + xcd; the 2 mt's of one nt adjacent (dist 8, same xcd).
    const int xcd = bx & 7;
    const int mt = (bx >> 3) & 1;
    const int nt = (bx >> 4) * 8 + xcd;
    const int tid = threadIdx.x, lane = tid & 63, wid = tid >> 6;
    const int wm = (wid >> 2) * 128, wn = (wid & 3) * 64;
    const int fr = lane & 15, quad = lane >> 4;
    floatx4 acc[8][4];
#pragma unroll
    for (int i = 0; i < 8; ++i)
#pragma unroll
        for (int j = 0; j < 4; ++j) acc[i][j] = (floatx4){0.f, 0.f, 0.f, 0.f};

    gemm_core256(w2b + (size_t)(mt * 256) * 1024, h1T + (size_t)(nt * 256) * 1024,
                 1024, 16, acc, lA, lB, wm, wn, fr, quad);

    const int n0g = b0 * 4096 + nt * 256;  // global flat (b,l); tiles never straddle b
    const int b = n0g >> 12;
    const int l_base = n0g & 4095;
    // swapped layout: m <- col (fr) = channel c, n <- row (quad*4 + reg) = l offset
    const int mb = mt * 256 + wm + fr;
    const int nb = wn + quad * 4;
#pragma unroll
    for (int i = 0; i < 8; ++i) {
        const int m = mb + i * 16;
        const float bv = b2[m];
        const size_t rowoff = ((size_t)(b * 512 + m)) * 4096 + l_base + nb;
#pragma unroll
        for (int j = 0; j < 4; ++j) {
            const float4 xv = *(const float4*)(x + rowoff + j * 16);
            float4 ov;
            ov.x = acc[i][j][0] + bv + xv.x;
            ov.y = acc[i][j][1] + bv + xv.y;
            ov.z = acc[i][j][2] + bv + xv.z;
            ov.w = acc[i][j][3] + bv + xv.w;
            *(float4*)(out + rowoff + j * 16) = ov;
        }
    }
}

extern "C" void kernel_launch(void* const* d_in, const int* in_sizes, int n_in,
                              void* d_out, int out_size, void* d_ws, size_t ws_size,
                              hipStream_t stream) {
    const float* x     = (const float*)d_in[0];
    const float* gamma = (const float*)d_in[1];
    const float* beta  = (const float*)d_in[2];
    const float* w1    = (const float*)d_in[3];
    const float* b1    = (const float*)d_in[4];
    const float* w2    = (const float*)d_in[5];
    const float* b2    = (const float*)d_in[6];
    float* out = (float*)d_out;

    char* ws = (char*)d_ws;
    float* pstats = (float*)ws;                    // 8 KB used
    u16* wb = (u16*)(ws + 65536);                  // 2 MiB: w1b then w2b
    char* chunkbase = ws + 65536 + (2u << 20);
    const size_t fixed = 65536 + (2u << 20);

    // choose smallest chunk count NC so xnT+h1T fit in ws
    const size_t per = (size_t)192 * 1024 * 1024;  // NC=1: 64 MiB xnT + 128 MiB h1T
    int NC = 16;
    if      (ws_size >= fixed + per)      NC = 1;
    else if (ws_size >= fixed + per / 2)  NC = 2;
    else if (ws_size >= fixed + per / 4)  NC = 4;
    else if (ws_size >= fixed + per / 8)  NC = 8;
    const int CB = 16 / NC;                        // batches per chunk
    u16* xnT = (u16*)chunkbase;
    u16* h1T = (u16*)(chunkbase + (size_t)CB * 4096 * 512 * 2);

    gn_stats_partial<<<1024, 256, 0, stream>>>(x, pstats);
    conv_w<<<1024, 256, 0, stream>>>(w1, w2, wb);
    for (int ch = 0; ch < NC; ++ch) {
        const int b0 = ch * CB;
        gn_norm_tr<<<CB * 512, 256, 0, stream>>>(x, gamma, beta, pstats, xnT, b0);
        gemm1<<<CB * 64, 512, 0, stream>>>(xnT, wb, b1, h1T);
        gemm2<<<CB * 32, 512, 0, stream>>>(wb + 524288, h1T, b2, x, out, b0);
    }
}

// Round 7
// 481.803 us; speedup vs baseline: 1.0227x; 1.0227x over previous
//
#include <hip/hip_runtime.h>
#include <cstdint>
#include <cstddef>

// FeedForward: GroupNorm(8) -> conv1x1 C->2C -> GELU(exact) -> conv1x1 2C->C -> +x
// B=16, C=512, L=4096. ALL I/O FP32. Internal: bf16 MFMA, fp32 accum.
//
// R11 changes:
//  - GEMM cores REVERTED to R6's proven 2-phase 128x128 dbuf structure (482us
//    ensemble). The 4-phase 256x256 experiment (R7-R10) plateaued at gemm1=136
//    vs R6's <=133 -- reduced-fidelity 8-phase doesn't reproduce the template
//    gain; cutting losses.
//  - gn_norm_tr reworked: top-5 max-filter shows all non-gemm kernels <135us,
//    but sum-accounting leaves ~200-250us for gn_stats+gn_norm_tr (floor ~55).
//    Old gn_norm_tr: 8192 blocks x 24KB traffic, 2 dependent loads/thread
//    before barrier -> latency/dispatch-bound. New: 4 l-subtiles per block
//    (grid 2048), 4 LDS T-buffers, all 16 float4 loads in flight before ONE
//    barrier, then 8 uint4 stores. LDS 36.9KB -> 4 blocks/CU.
//  - Kept: A&S erf GELU, swapped mfma(bb,af) vectorized epilogues, XCD
//    swizzles, global_load_lds staging, XOR k-swizzle.

typedef unsigned short u16;
typedef unsigned int u32;
typedef __attribute__((ext_vector_type(8))) __bf16 bf16x8;
typedef __attribute__((ext_vector_type(4))) float floatx4;

#define BM 128
#define BN 128
#define BKK 64

__device__ __forceinline__ u16 f2bf(float f) {
    union { float f; u32 u; } v; v.f = f;
    u32 u = v.u;
    return (u16)((u + 0x7fffu + ((u >> 16) & 1u)) >> 16);  // RNE
}

// GELU(v) = 0.5 v (1 + erf(v/sqrt(2))); erf via A&S 7.1.26, |err| <= 1.5e-7.
__device__ __forceinline__ float gelu_exact(float v) {
    const float x = fabsf(v) * 0.70710678118654752f;
    const float t = __builtin_amdgcn_rcpf(fmaf(0.3275911f, x, 1.0f));
    float p = fmaf(1.061405429f, t, -1.453152027f);
    p = fmaf(p, t, 1.421413741f);
    p = fmaf(p, t, -0.284496736f);
    p = fmaf(p, t, 0.254829592f);
    p = p * t;
    const float e = __expf(-x * x);            // v_exp_f32
    const float er = fmaf(-p, e, 1.0f);        // erf(|x|)
    const float s = copysignf(er, v);          // sign restore
    return 0.5f * v * (1.0f + s);
}

__device__ __forceinline__ void async_cp16(u16* lds, const u16* g) {
    __builtin_amdgcn_global_load_lds(
        (const __attribute__((address_space(1))) u32*)g,
        (__attribute__((address_space(3))) u32*)lds,
        16, 0, 0);
}

// ---------------- kernel 1: partial group stats ----------------
__global__ __launch_bounds__(256) void gn_stats_partial(const float* __restrict__ x,
                                                        float* __restrict__ pstats) {
    const int bx = blockIdx.x;  // bg*8 + slice
    const float4* p = (const float4*)(x + (size_t)(bx >> 3) * 262144 + (size_t)(bx & 7) * 32768);
    float s = 0.f, ss = 0.f;
    for (int i = threadIdx.x; i < 8192; i += 256) {
        float4 v = p[i];
        s += v.x + v.y + v.z + v.w;
        ss += v.x * v.x + v.y * v.y + v.z * v.z + v.w * v.w;
    }
#pragma unroll
    for (int off = 32; off > 0; off >>= 1) {
        s  += __shfl_down(s, off, 64);
        ss += __shfl_down(ss, off, 64);
    }
    __shared__ float rs[8];
    const int wv = threadIdx.x >> 6;
    if ((threadIdx.x & 63) == 0) { rs[wv * 2] = s; rs[wv * 2 + 1] = ss; }
    __syncthreads();
    if (threadIdx.x == 0) {
        pstats[bx * 2]     = rs[0] + rs[2] + rs[4] + rs[6];
        pstats[bx * 2 + 1] = rs[1] + rs[3] + rs[5] + rs[7];
    }
}

// ---------------- kernel 2: weights fp32 -> bf16 ----------------
__global__ __launch_bounds__(256) void conv_w(const float* __restrict__ w1,
                                              const float* __restrict__ w2,
                                              u16* __restrict__ wb) {
    const int idx = (blockIdx.x * 256 + threadIdx.x) * 4;  // < 1048576
    const float4 v = (idx < 524288) ? *(const float4*)(w1 + idx)
                                    : *(const float4*)(w2 + (idx - 524288));
    ushort4 o;
    o.x = f2bf(v.x); o.y = f2bf(v.y); o.z = f2bf(v.z); o.w = f2bf(v.w);
    *(ushort4*)(wb + idx) = o;
}

// ---------------- kernel 3: normalize + transpose (fp32 -> bf16) ----------------
// 4 l-subtiles (64l x 64c each) per block; 4 T-buffers so ALL loads are in
// flight before the single barrier (old version: 2 dependent loads/block ->
// latency-bound at 8192 tiny blocks).
__global__ __launch_bounds__(256) void gn_norm_tr(const float* __restrict__ x,
                                                  const float* __restrict__ gamma,
                                                  const float* __restrict__ beta,
                                                  const float* __restrict__ pstats,
                                                  u16* __restrict__ xnT, int b0) {
    __shared__ u16 T[4][64][72];  // [q][l][c], c-groups XOR-swizzled by (l>>3)&7
    const int bx = blockIdx.x;
    const int l4 = bx & 15;          // 16 l-supertiles of 256
    const int ct = (bx >> 4) & 7;    // 8 c-tiles (== groups)
    const int bl = bx >> 7;          // batch within chunk
    const int b = b0 + bl;
    const int c0 = ct * 64, l0 = l4 * 256;
    const int g = ct;                // tile spans exactly one group
    float S = 0.f, SS = 0.f;
#pragma unroll
    for (int s2 = 0; s2 < 8; ++s2) {
        S  += pstats[((b * 8 + g) * 8 + s2) * 2];
        SS += pstats[((b * 8 + g) * 8 + s2) * 2 + 1];
    }
    const float inv = 1.f / 262144.f;
    const float mean = S * inv;
    const float var = SS * inv - mean * mean;  // population var (jnp.var)
    const float rstd = rsqrtf(var + 1e-5f);

    const int t = threadIdx.x;
    const int cl = t >> 3;          // 0..31  (c within tile, low 32)
    const int lo = (t & 7) * 8;     // 8 l's per thread
    const int sw = t & 7;           // == (l>>3)&7 for this thread's l's
#pragma unroll
    for (int h = 0; h < 2; ++h) {
        const int c = c0 + cl + h * 32;
        const float sc = rstd * gamma[c];
        const float sh = beta[c] - mean * sc;
        const int ccol = cl + h * 32;
        const int col = (((ccol >> 3) ^ sw) << 3) + (ccol & 7);
        const float* srcr = x + ((size_t)(b * 512 + c) * 4096 + l0 + lo);
#pragma unroll
        for (int q = 0; q < 4; ++q) {
            const float* src = srcr + q * 64;
            float4 a = *(const float4*)src;
            float4 bq = *(const float4*)(src + 4);
            float vv[8] = {a.x, a.y, a.z, a.w, bq.x, bq.y, bq.z, bq.w};
#pragma unroll
            for (int k = 0; k < 8; ++k)
                T[q][lo + k][col] = f2bf(fmaf(vv[k], sc, sh));
        }
    }
    __syncthreads();
    const int ll = t >> 3;
    const int co = (t & 7) * 8, cog = t & 7;
#pragma unroll
    for (int h = 0; h < 2; ++h) {
        const int l = ll + h * 32;
        const int colb = (cog ^ ((l >> 3) & 7)) << 3;
#pragma unroll
        for (int q = 0; q < 4; ++q) {
            const uint4* srcv = (const uint4*)&T[q][l][colb];
            *(uint4*)(xnT + ((size_t)(bl * 4096 + l0 + q * 64 + l) * 512 + c0 + co)) = *srcv;
        }
    }
}

// ---------------- GEMM core (gemm_bt): C[m][n] = sum_k A[m][k]*B[n][k] ----------------
// R6 structure (proven): double-buffered LDS, global_load_lds width=16, XOR
// k-swizzle baked into the GLOBAL fetch address (LDS dest lane-linear). Per
// K-step: issue async loads -> buf^1 ; ds_read+MFMA on buf ; __syncthreads.
// MFMA operand order SWAPPED (bb first): C/D maps col=lane&15 -> m (af rows),
// row=quad*4+reg -> n (bb rows) -> lane's 4 acc regs are consecutive n.
__device__ __forceinline__ void gemm_core(const u16* __restrict__ Ag,  // [*][K] bf16
                                          const u16* __restrict__ Bg,  // [*][K] bf16
                                          int K, floatx4 acc[4][4],
                                          u16* lA, u16* lB,
                                          int wm, int wn, int fr, int quad) {
    const int t = threadIdx.x;

    auto stage = [&](int buf, int kt) {
        u16* dA = lA + buf * (BM * BKK);
        u16* dB = lB + buf * (BN * BKK);
#pragma unroll
        for (int s = 0; s < 4; ++s) {
            int idx = s * 256 + t;
            int row = idx >> 3;
            int kg = (idx & 7) ^ (row & 7);
            async_cp16(dA + idx * 8, Ag + (size_t)row * K + kt + kg * 8);
        }
#pragma unroll
        for (int s = 0; s < 4; ++s) {
            int idx = s * 256 + t;
            int row = idx >> 3;
            int kg = (idx & 7) ^ (row & 7);
            async_cp16(dB + idx * 8, Bg + (size_t)row * K + kt + kg * 8);
        }
    };

    stage(0, 0);
    __syncthreads();  // buf0 ready
    int cur = 0;
    for (int kt = 0; kt < K; kt += BKK) {
        if (kt + BKK < K) stage(cur ^ 1, kt + BKK);  // in flight across MFMA phase
        const u16* bA = lA + cur * (BM * BKK);
        const u16* bB = lB + cur * (BN * BKK);
#pragma unroll
        for (int kk = 0; kk < BKK; kk += 32) {
            bf16x8 af[4], bb[4];
#pragma unroll
            for (int i = 0; i < 4; ++i) {
                int row = wm + i * 16 + fr;
                int kg = ((kk >> 3) + quad) ^ (fr & 7);
                af[i] = *(const bf16x8*)(bA + row * BKK + kg * 8);
            }
#pragma unroll
            for (int j = 0; j < 4; ++j) {
                int row = wn + j * 16 + fr;
                int kg = ((kk >> 3) + quad) ^ (fr & 7);
                bb[j] = *(const bf16x8*)(bB + row * BKK + kg * 8);
            }
#pragma unroll
            for (int i = 0; i < 4; ++i)
#pragma unroll
                for (int j = 0; j < 4; ++j)
                    acc[i][j] = __builtin_amdgcn_mfma_f32_16x16x32_bf16(bb[j], af[i], acc[i][j], 0, 0, 0);
        }
        __syncthreads();  // drains prefetch (mostly complete) + releases buf[cur]
        cur ^= 1;
    }
}

// ---------------- kernel 4: GEMM1 + bias + exact GELU -> h1T (bf16) ----------------
__global__ __launch_bounds__(256) void gemm1(const u16* __restrict__ xnT,
                                             const u16* __restrict__ w1b,
                                             const float* __restrict__ b1,
                                             u16* __restrict__ h1T) {
    __shared__ uint4 lAq[2 * BM * BKK / 8], lBq[2 * BN * BKK / 8];
    u16* lA = (u16*)lAq; u16* lB = (u16*)lBq;
    const int bx = blockIdx.x;
    // XCD swizzle: mt%8 == bx%8, the 8 nt's of one mt adjacent in dispatch.
    const int nt = (bx >> 3) & 7;
    const int mt = (bx & 7) | ((bx >> 6) << 3);
    const int t = threadIdx.x, lane = t & 63, wv = t >> 6;
    const int wm = (wv & 1) * 64, wn = (wv >> 1) * 64;
    const int fr = lane & 15, quad = lane >> 4;
    floatx4 acc[4][4];
#pragma unroll
    for (int i = 0; i < 4; ++i)
#pragma unroll
        for (int j = 0; j < 4; ++j) acc[i][j] = (floatx4){0.f, 0.f, 0.f, 0.f};

    gemm_core(xnT + (size_t)(mt * BM) * 512, w1b + (size_t)(nt * BN) * 512, 512,
              acc, lA, lB, wm, wn, fr, quad);

    // swapped layout: m <- col (fr), n <- row (quad*4 + reg)
    const int mb = mt * BM + wm + fr;
    const int nb = nt * BN + wn + quad * 4;
#pragma unroll
    for (int j = 0; j < 4; ++j) {
        const int n0 = nb + j * 16;
        const float4 bv = *(const float4*)(b1 + n0);
#pragma unroll
        for (int i = 0; i < 4; ++i) {
            const int m = mb + i * 16;
            ushort4 o;
            o.x = f2bf(gelu_exact(acc[i][j][0] + bv.x));
            o.y = f2bf(gelu_exact(acc[i][j][1] + bv.y));
            o.z = f2bf(gelu_exact(acc[i][j][2] + bv.z));
            o.w = f2bf(gelu_exact(acc[i][j][3] + bv.w));
            *(ushort4*)(h1T + (size_t)m * 1024 + n0) = o;
        }
    }
}

// ---------------- kernel 5: GEMM2 + bias + residual -> out (fp32) ----------------
__global__ __launch_bounds__(256) void gemm2(const u16* __restrict__ w2b,
                                             const u16* __restrict__ h1T,
                                             const float* __restrict__ b2,
                                             const float* __restrict__ x,
                                             float* __restrict__ out, int b0) {
    __shared__ uint4 lAq[2 * BM * BKK / 8], lBq[2 * BN * BKK / 8];
    u16* lA = (u16*)lAq; u16* lB = (u16*)lBq;
    const int bx = blockIdx.x;
    // XCD swizzle: nt%8 == bx%8, the 4 mt's of one nt adjacent in dispatch.
    const int mt = (bx >> 3) & 3;
    const int nt = (bx & 7) | ((bx >> 5) << 3);
    const int t = threadIdx.x, lane = t & 63, wv = t >> 6;
    const int wm = (wv & 1) * 64, wn = (wv >> 1) * 64;
    const int fr = lane & 15, quad = lane >> 4;
    floatx4 acc[4][4];
#pragma unroll
    for (int i = 0; i < 4; ++i)
#pragma unroll
        for (int j = 0; j < 4; ++j) acc[i][j] = (floatx4){0.f, 0.f, 0.f, 0.f};

    gemm_core(w2b + (size_t)(mt * BM) * 1024, h1T + (size_t)(nt * BN) * 1024, 1024,
              acc, lA, lB, wm, wn, fr, quad);

    const int n0g = b0 * 4096 + nt * BN;  // global flat (b,l); tiles never straddle b
    const int b = n0g >> 12;
    const int l_base = n0g & 4095;
    // swapped layout: m <- col (fr) = channel c, n <- row (quad*4 + reg) = l offset
    const int mb = mt * BM + wm + fr;
    const int nb = wn + quad * 4;
#pragma unroll
    for (int i = 0; i < 4; ++i) {
        const int m = mb + i * 16;
        const float bv = b2[m];
        const size_t rowoff = ((size_t)(b * 512 + m)) * 4096 + l_base + nb;
#pragma unroll
        for (int j = 0; j < 4; ++j) {
            const float4 xv = *(const float4*)(x + rowoff + j * 16);
            float4 ov;
            ov.x = acc[i][j][0] + bv + xv.x;
            ov.y = acc[i][j][1] + bv + xv.y;
            ov.z = acc[i][j][2] + bv + xv.z;
            ov.w = acc[i][j][3] + bv + xv.w;
            *(float4*)(out + rowoff + j * 16) = ov;
        }
    }
}

extern "C" void kernel_launch(void* const* d_in, const int* in_sizes, int n_in,
                              void* d_out, int out_size, void* d_ws, size_t ws_size,
                              hipStream_t stream) {
    const float* x     = (const float*)d_in[0];
    const float* gamma = (const float*)d_in[1];
    const float* beta  = (const float*)d_in[2];
    const float* w1    = (const float*)d_in[3];
    const float* b1    = (const float*)d_in[4];
    const float* w2    = (const float*)d_in[5];
    const float* b2    = (const float*)d_in[6];
    float* out = (float*)d_out;

    char* ws = (char*)d_ws;
    float* pstats = (float*)ws;                    // 8 KB used
    u16* wb = (u16*)(ws + 65536);                  // 2 MiB: w1b then w2b
    char* chunkbase = ws + 65536 + (2u << 20);
    const size_t fixed = 65536 + (2u << 20);

    // choose smallest chunk count NC so xnT+h1T fit in ws
    const size_t per = (size_t)192 * 1024 * 1024;  // NC=1: 64 MiB xnT + 128 MiB h1T
    int NC = 16;
    if      (ws_size >= fixed + per)      NC = 1;
    else if (ws_size >= fixed + per / 2)  NC = 2;
    else if (ws_size >= fixed + per / 4)  NC = 4;
    else if (ws_size >= fixed + per / 8)  NC = 8;
    const int CB = 16 / NC;                        // batches per chunk
    u16* xnT = (u16*)chunkbase;
    u16* h1T = (u16*)(chunkbase + (size_t)CB * 4096 * 512 * 2);

    gn_stats_partial<<<1024, 256, 0, stream>>>(x, pstats);
    conv_w<<<1024, 256, 0, stream>>>(w1, w2, wb);
    for (int ch = 0; ch < NC; ++ch) {
        const int b0 = ch * CB;
        gn_norm_tr<<<CB * 128, 256, 0, stream>>>(x, gamma, beta, pstats, xnT, b0);
        gemm1<<<CB * 32 * 8, 256, 0, stream>>>(xnT, wb, b1, h1T);
        gemm2<<<CB * 32 * 4, 256, 0, stream>>>(wb + 524288, h1T, b2, x, out, b0);
    }
}